// Round 1
// baseline (106.968 us; speedup 1.0000x reference)
//
#include <hip/hip_runtime.h>

#define N_SPOTS 50000
#define N_NEIGH 32
#define N_PROG  128

#define NBLOCKS 1024
#define BLOCK   256
#define WAVES_PER_BLOCK (BLOCK / 64)
#define TOTAL_WAVES (NBLOCKS * WAVES_PER_BLOCK)

// One wave per spot (grid-strided). Lane l holds p[spot][2l .. 2l+1].
__global__ __launch_bounds__(BLOCK) void consistency_partial_kernel(
    const float* __restrict__ probs,
    const float* __restrict__ w,
    const int*   __restrict__ idx,
    float* __restrict__ partials)
{
    const int wave_in_block = threadIdx.x >> 6;
    const int lane          = threadIdx.x & 63;
    const int wave_global   = blockIdx.x * WAVES_PER_BLOCK + wave_in_block;

    float acc = 0.0f;

    for (int spot = wave_global; spot < N_SPOTS; spot += TOTAL_WAVES) {
        // own row: 2 contiguous floats per lane (coalesced 512B per wave)
        const float2 p = *reinterpret_cast<const float2*>(
            probs + (size_t)spot * N_PROG + lane * 2);

        // stage this spot's 32 idx/w values in lanes 0..31
        int   my_idx = 0;
        float my_w   = 0.0f;
        if (lane < N_NEIGH) {
            my_idx = idx[spot * N_NEIGH + lane];
            my_w   = w  [spot * N_NEIGH + lane];
        }

        #pragma unroll 8
        for (int j = 0; j < N_NEIGH; ++j) {
            const int   nb = __shfl(my_idx, j, 64);
            const float wj = __shfl(my_w,   j, 64);
            const float2 q = *reinterpret_cast<const float2*>(
                probs + (size_t)nb * N_PROG + lane * 2);
            const float dx = p.x - q.x;
            const float dy = p.y - q.y;
            acc = fmaf(wj, fmaf(dx, dx, dy * dy), acc);
        }
    }

    // wave reduction (64 lanes)
    #pragma unroll
    for (int off = 32; off > 0; off >>= 1)
        acc += __shfl_down(acc, off, 64);

    __shared__ float s[WAVES_PER_BLOCK];
    if (lane == 0) s[wave_in_block] = acc;
    __syncthreads();
    if (threadIdx.x == 0) {
        float t = 0.0f;
        #pragma unroll
        for (int v = 0; v < WAVES_PER_BLOCK; ++v) t += s[v];
        partials[blockIdx.x] = t;
    }
}

// Single-block deterministic finalize: sum partials, divide by n.
__global__ __launch_bounds__(BLOCK) void finalize_kernel(
    const float* __restrict__ partials,
    float* __restrict__ out)
{
    const int wave = threadIdx.x >> 6;
    const int lane = threadIdx.x & 63;

    float acc = 0.0f;
    for (int i = threadIdx.x; i < NBLOCKS; i += BLOCK)
        acc += partials[i];

    #pragma unroll
    for (int off = 32; off > 0; off >>= 1)
        acc += __shfl_down(acc, off, 64);

    __shared__ float s[WAVES_PER_BLOCK];
    if (lane == 0) s[wave] = acc;
    __syncthreads();
    if (threadIdx.x == 0) {
        float t = 0.0f;
        #pragma unroll
        for (int v = 0; v < WAVES_PER_BLOCK; ++v) t += s[v];
        out[0] = t / (float)N_SPOTS;
    }
}

extern "C" void kernel_launch(void* const* d_in, const int* in_sizes, int n_in,
                              void* d_out, int out_size, void* d_ws, size_t ws_size,
                              hipStream_t stream) {
    const float* probs = (const float*)d_in[0];   // [N_SPOTS, N_PROG] f32
    const float* w     = (const float*)d_in[1];   // [N_SPOTS, N_NEIGH] f32
    const int*   idx   = (const int*)  d_in[2];   // [N_SPOTS, N_NEIGH] i32
    float* out      = (float*)d_out;
    float* partials = (float*)d_ws;               // NBLOCKS floats (4 KB)

    consistency_partial_kernel<<<NBLOCKS, BLOCK, 0, stream>>>(probs, w, idx, partials);
    finalize_kernel<<<1, BLOCK, 0, stream>>>(partials, out);
}